// Round 1
// baseline (351.364 us; speedup 1.0000x reference)
//
#include <hip/hip_runtime.h>
#include <hip/hip_bf16.h>
#include <stdint.h>

#define N_NODES 50000
#define N_EDGES 800000
#define D_H 128
#define D_E 64
#define HID 128

typedef __attribute__((ext_vector_type(8))) short bf16x8;
typedef __attribute__((ext_vector_type(4))) short s16x4;
typedef __attribute__((ext_vector_type(4))) float f32x4;

__device__ __forceinline__ unsigned short f2bf(float x) {
    unsigned int u = __float_as_uint(x);
    u += 0x7FFFu + ((u >> 16) & 1u);   // round-to-nearest-even
    return (unsigned short)(u >> 16);
}

// ---------------- zero the scatter-max accumulator ----------------
__global__ void zero_f32(float* __restrict__ p, int n4) {
    int i = blockIdx.x * blockDim.x + threadIdx.x;
    if (i < n4) ((f32x4*)p)[i] = f32x4{0.f, 0.f, 0.f, 0.f};
}

// ---------------- edge MLP + scatter-max ----------------
// y = relu(concat(H[src], Xe) @ W1); atomicMax into gmax[dst].
// M-tile = 128 edges, K = 192, N = 128 (4 waves x 32 cols).
__global__ __launch_bounds__(256, 2)
void edge_mlp_scatter(const float* __restrict__ H,
                      const int* __restrict__ idx,
                      const float* __restrict__ Xe,
                      const float* __restrict__ W1,
                      int* __restrict__ gmax) {
    __shared__ unsigned short sX[128][200];   // 192 + 8 pad (bank rotate by 4 dwords)
    __shared__ int sSrc[128];
    __shared__ int sDst[128];

    const int tid  = threadIdx.x;
    const int wave = tid >> 6;
    const int lane = tid & 63;
    const int base = blockIdx.x * 128;

    if (tid < 128) sSrc[tid] = idx[base + tid];
    else           sDst[tid - 128] = idx[N_EDGES + base + (tid - 128)];
    __syncthreads();

    // B fragments (W1) held in registers: wave covers cols [wave*32, wave*32+32)
    const int col = lane & 15;
    const int kr0 = (lane >> 4) * 8;
    bf16x8 bfrag[6][2];
    #pragma unroll
    for (int ks = 0; ks < 6; ++ks) {
        #pragma unroll
        for (int nf = 0; nf < 2; ++nf) {
            const int n  = wave * 32 + nf * 16 + col;
            const int kb = ks * 32 + kr0;
            bf16x8 b;
            #pragma unroll
            for (int f = 0; f < 8; ++f) b[f] = (short)f2bf(W1[(kb + f) * HID + n]);
            bfrag[ks][nf] = b;
        }
    }

    // stage gathered H part: cols 0..127
    #pragma unroll
    for (int it = 0; it < 16; ++it) {
        const int i   = tid + it * 256;
        const int row = i >> 5;
        const int c4  = (i & 31) * 4;
        const f32x4 v = *(const f32x4*)(H + (size_t)sSrc[row] * D_H + c4);
        s16x4 pk = { (short)f2bf(v[0]), (short)f2bf(v[1]),
                     (short)f2bf(v[2]), (short)f2bf(v[3]) };
        *(s16x4*)&sX[row][c4] = pk;
    }
    // stage Xe part: cols 128..191 (fully coalesced)
    #pragma unroll
    for (int it = 0; it < 8; ++it) {
        const int i   = tid + it * 256;
        const int row = i >> 4;
        const int c4  = (i & 15) * 4;
        const f32x4 v = *(const f32x4*)(Xe + (size_t)(base + row) * D_E + c4);
        s16x4 pk = { (short)f2bf(v[0]), (short)f2bf(v[1]),
                     (short)f2bf(v[2]), (short)f2bf(v[3]) };
        *(s16x4*)&sX[row][128 + c4] = pk;
    }
    __syncthreads();

    f32x4 acc[8][2];
    #pragma unroll
    for (int m = 0; m < 8; ++m) {
        acc[m][0] = f32x4{0.f, 0.f, 0.f, 0.f};
        acc[m][1] = f32x4{0.f, 0.f, 0.f, 0.f};
    }

    const int arow = lane & 15;
    #pragma unroll
    for (int ks = 0; ks < 6; ++ks) {
        #pragma unroll
        for (int m = 0; m < 8; ++m) {
            bf16x8 a = *(const bf16x8*)&sX[m * 16 + arow][ks * 32 + kr0];
            acc[m][0] = __builtin_amdgcn_mfma_f32_16x16x32_bf16(a, bfrag[ks][0], acc[m][0], 0, 0, 0);
            acc[m][1] = __builtin_amdgcn_mfma_f32_16x16x32_bf16(a, bfrag[ks][1], acc[m][1], 0, 0, 0);
        }
    }

    // relu + scatter-max (integer atomicMax is order-correct for nonneg floats)
    const int rb = (lane >> 4) * 4;
    #pragma unroll
    for (int m = 0; m < 8; ++m) {
        #pragma unroll
        for (int r = 0; r < 4; ++r) {
            const int node = sDst[m * 16 + rb + r];
            const size_t o = (size_t)node * HID + wave * 32 + col;
            const float v0 = acc[m][0][r];
            const float v1 = acc[m][1][r];
            if (v0 > 0.f) atomicMax(gmax + o,      __float_as_int(v0));
            if (v1 > 0.f) atomicMax(gmax + o + 16, __float_as_int(v1));
        }
    }
}

// ---------------- node MLP + residual ----------------
// out = relu(concat(H, gmax) @ W2) + H.  M-tile = 64 nodes, K = 256, N = 128.
__global__ __launch_bounds__(256, 2)
void node_mlp(const float* __restrict__ H,
              const float* __restrict__ gmax,
              const float* __restrict__ W2,
              float* __restrict__ out) {
    __shared__ unsigned short sA[64][264];    // 256 + 8 pad; 33.8 KB

    const int tid  = threadIdx.x;
    const int wave = tid >> 6;
    const int lane = tid & 63;
    const int base = blockIdx.x * 64;

    const int col = lane & 15;
    const int kr0 = (lane >> 4) * 8;
    bf16x8 bfrag[8][2];
    #pragma unroll
    for (int ks = 0; ks < 8; ++ks) {
        #pragma unroll
        for (int nf = 0; nf < 2; ++nf) {
            const int n  = wave * 32 + nf * 16 + col;
            const int kb = ks * 32 + kr0;
            bf16x8 b;
            #pragma unroll
            for (int f = 0; f < 8; ++f) b[f] = (short)f2bf(W2[(kb + f) * HID + n]);
            bfrag[ks][nf] = b;
        }
    }

    // stage concat(H, gmax): 64 rows x 256 cols
    #pragma unroll
    for (int it = 0; it < 16; ++it) {
        const int i   = tid + it * 256;
        const int row = i >> 6;
        const int c4  = (i & 63) * 4;
        int node = base + row;
        if (node >= N_NODES) node = N_NODES - 1;   // clamp; stores are guarded
        const float* p = (c4 < 128) ? (H    + (size_t)node * D_H + c4)
                                    : (gmax + (size_t)node * HID + (c4 - 128));
        const f32x4 v = *(const f32x4*)p;
        s16x4 pk = { (short)f2bf(v[0]), (short)f2bf(v[1]),
                     (short)f2bf(v[2]), (short)f2bf(v[3]) };
        *(s16x4*)&sA[row][c4] = pk;
    }
    __syncthreads();

    f32x4 acc[4][2];
    #pragma unroll
    for (int m = 0; m < 4; ++m) {
        acc[m][0] = f32x4{0.f, 0.f, 0.f, 0.f};
        acc[m][1] = f32x4{0.f, 0.f, 0.f, 0.f};
    }

    const int arow = lane & 15;
    #pragma unroll
    for (int ks = 0; ks < 8; ++ks) {
        #pragma unroll
        for (int m = 0; m < 4; ++m) {
            bf16x8 a = *(const bf16x8*)&sA[m * 16 + arow][ks * 32 + kr0];
            acc[m][0] = __builtin_amdgcn_mfma_f32_16x16x32_bf16(a, bfrag[ks][0], acc[m][0], 0, 0, 0);
            acc[m][1] = __builtin_amdgcn_mfma_f32_16x16x32_bf16(a, bfrag[ks][1], acc[m][1], 0, 0, 0);
        }
    }

    const int rb = (lane >> 4) * 4;
    #pragma unroll
    for (int m = 0; m < 4; ++m) {
        #pragma unroll
        for (int r = 0; r < 4; ++r) {
            const int node = base + m * 16 + rb + r;
            if (node < N_NODES) {
                const size_t o = (size_t)node * HID + wave * 32 + col;
                out[o]      = fmaxf(acc[m][0][r], 0.f) + H[o];
                out[o + 16] = fmaxf(acc[m][1][r], 0.f) + H[o + 16];
            }
        }
    }
}

extern "C" void kernel_launch(void* const* d_in, const int* in_sizes, int n_in,
                              void* d_out, int out_size, void* d_ws, size_t ws_size,
                              hipStream_t stream) {
    const float* H  = (const float*)d_in[0];
    const int*   idx = (const int*)d_in[1];
    const float* Xe = (const float*)d_in[2];
    const float* W1 = (const float*)d_in[3];
    const float* W2 = (const float*)d_in[4];
    float* out  = (float*)d_out;
    float* gmax = (float*)d_ws;   // 50000*128 f32 = 25.6 MB scratch

    const int n4 = N_NODES * HID / 4;
    zero_f32<<<(n4 + 255) / 256, 256, 0, stream>>>(gmax, n4);
    edge_mlp_scatter<<<N_EDGES / 128, 256, 0, stream>>>(H, idx, Xe, W1, (int*)gmax);
    node_mlp<<<(N_NODES + 63) / 64, 256, 0, stream>>>(H, gmax, W2, out);
}

// Round 2
// 274.500 us; speedup vs baseline: 1.2800x; 1.2800x over previous
//
#include <hip/hip_runtime.h>
#include <hip/hip_bf16.h>
#include <stdint.h>

#define N_NODES 50000
#define N_EDGES 800000
#define D_H 128
#define D_E 64
#define HID 128

#define NODES_PER_BLK 16
#define N_BLOCKS (N_NODES / NODES_PER_BLK)   // 3125 exactly
#define SCAN_B 512
#define N_CHUNKS ((N_NODES + SCAN_B - 1) / SCAN_B)  // 98

typedef __attribute__((ext_vector_type(8))) short bf16x8;
typedef __attribute__((ext_vector_type(4))) short s16x4;
typedef __attribute__((ext_vector_type(4))) float f32x4;
typedef __attribute__((ext_vector_type(4))) int i32x4;

__device__ __forceinline__ unsigned short f2bf(float x) {
    unsigned int u = __float_as_uint(x);
    u += 0x7FFFu + ((u >> 16) & 1u);   // round-to-nearest-even
    return (unsigned short)(u >> 16);
}

// ---------------- CSR build: histogram / scan / scatter ----------------
__global__ void zero_deg(int* __restrict__ deg) {
    int i = blockIdx.x * blockDim.x + threadIdx.x;
    if (i < N_NODES / 4) ((i32x4*)deg)[i] = i32x4{0, 0, 0, 0};
}

__global__ void hist(const int* __restrict__ idx, int* __restrict__ deg) {
    int i = blockIdx.x * blockDim.x + threadIdx.x;
    atomicAdd(&deg[idx[N_EDGES + i]], 1);
}

__global__ void scan_a(const int* __restrict__ deg, int* __restrict__ sc,
                       int* __restrict__ totals) {
    __shared__ int s[SCAN_B];
    const int tid = threadIdx.x;
    const int i = blockIdx.x * SCAN_B + tid;
    const int v = (i < N_NODES) ? deg[i] : 0;
    s[tid] = v;
    __syncthreads();
    for (int o = 1; o < SCAN_B; o <<= 1) {
        int t = (tid >= o) ? s[tid - o] : 0;
        __syncthreads();
        s[tid] += t;
        __syncthreads();
    }
    if (i < N_NODES) sc[i] = s[tid] - v;          // exclusive within chunk
    if (tid == SCAN_B - 1) totals[blockIdx.x] = s[SCAN_B - 1];
}

__global__ void scan_b(int* __restrict__ totals) {
    __shared__ int s[128];
    const int tid = threadIdx.x;
    const int v = (tid < N_CHUNKS) ? totals[tid] : 0;
    s[tid] = v;
    __syncthreads();
    for (int o = 1; o < 128; o <<= 1) {
        int t = (tid >= o) ? s[tid - o] : 0;
        __syncthreads();
        s[tid] += t;
        __syncthreads();
    }
    if (tid < N_CHUNKS) totals[tid] = s[tid] - v; // exclusive chunk offsets
}

__global__ void scan_c(const int* __restrict__ sc, const int* __restrict__ totals,
                       int* __restrict__ offsets, int* __restrict__ cursor) {
    const int i = blockIdx.x * SCAN_B + threadIdx.x;
    if (i < N_NODES) {
        const int o = sc[i] + totals[blockIdx.x];
        offsets[i] = o;
        cursor[i]  = o;
    }
    if (i == 0) offsets[N_NODES] = N_EDGES;
}

__global__ void scatter(const int* __restrict__ idx, int* __restrict__ cursor,
                        int* __restrict__ perm) {
    int i = blockIdx.x * blockDim.x + threadIdx.x;
    const int d = idx[N_EDGES + i];
    const int p = atomicAdd(&cursor[d], 1);
    perm[p] = i;
}

// ---------------- edge MLP + in-LDS segmented max (no global atomics) ----------------
// Block owns 16 dst nodes; iterates their (sorted) edges in 128-row MFMA tiles.
__global__ __launch_bounds__(256, 2)
void edge_sorted(const float* __restrict__ H,
                 const int* __restrict__ idx,
                 const float* __restrict__ Xe,
                 const float* __restrict__ W1,
                 const int* __restrict__ offsets,
                 const int* __restrict__ perm,
                 unsigned short* __restrict__ gmax) {
    __shared__ unsigned short sX[128][200];   // 51.2 KB, +8 pad
    __shared__ float ymax[17][132];           // row 16 = dummy; 9.0 KB
    __shared__ int sSrc[128];
    __shared__ int sE[128];
    __shared__ unsigned char rowNode[128];
    __shared__ int sOff[NODES_PER_BLK + 1];

    const int tid  = threadIdx.x;
    const int wave = tid >> 6;
    const int lane = tid & 63;
    const int nodeBase = blockIdx.x * NODES_PER_BLK;

    if (tid <= NODES_PER_BLK) sOff[tid] = offsets[nodeBase + tid];
    for (int i = tid; i < 17 * 132; i += 256) ((float*)ymax)[i] = 0.f;

    // W1 B-fragments in registers (wave covers cols [wave*32, wave*32+32))
    const int col = lane & 15;
    const int kr0 = (lane >> 4) * 8;
    bf16x8 bfrag[6][2];
    #pragma unroll
    for (int ks = 0; ks < 6; ++ks) {
        #pragma unroll
        for (int nf = 0; nf < 2; ++nf) {
            const int n  = wave * 32 + nf * 16 + col;
            const int kb = ks * 32 + kr0;
            bf16x8 b;
            #pragma unroll
            for (int f = 0; f < 8; ++f) b[f] = (short)f2bf(W1[(kb + f) * HID + n]);
            bfrag[ks][nf] = b;
        }
    }
    __syncthreads();

    const int eBeg = sOff[0];
    const int eEnd = sOff[NODES_PER_BLK];
    const int nE   = eEnd - eBeg;
    const int nTiles = (nE + 127) >> 7;

    const int arow = lane & 15;
    const int rb   = (lane >> 4) * 4;

    for (int t = 0; t < nTiles; ++t) {
        // --- per-row prep: edge id, src node, local dst slot
        if (tid < 128) {
            const int p = eBeg + t * 128 + tid;
            int e, g;
            if (p < eEnd) {
                e = perm[p];
                g = 0;
                #pragma unroll
                for (int k = 1; k < NODES_PER_BLK; ++k) g += (p >= sOff[k]);
            } else {
                e = perm[eBeg];   // valid edge, result discarded
                g = NODES_PER_BLK;
            }
            sE[tid] = e;
            sSrc[tid] = idx[e];
            rowNode[tid] = (unsigned char)g;
        }
        __syncthreads();

        // --- stage gathered H part: cols 0..127
        #pragma unroll
        for (int it = 0; it < 16; ++it) {
            const int i   = tid + it * 256;
            const int row = i >> 5;
            const int c4  = (i & 31) * 4;
            const f32x4 v = *(const f32x4*)(H + (size_t)sSrc[row] * D_H + c4);
            s16x4 pk = { (short)f2bf(v[0]), (short)f2bf(v[1]),
                         (short)f2bf(v[2]), (short)f2bf(v[3]) };
            *(s16x4*)&sX[row][c4] = pk;
        }
        // --- stage Xe part: cols 128..191 (row-gathered via perm)
        #pragma unroll
        for (int it = 0; it < 8; ++it) {
            const int i   = tid + it * 256;
            const int row = i >> 4;
            const int c4  = (i & 15) * 4;
            const f32x4 v = *(const f32x4*)(Xe + (size_t)sE[row] * D_E + c4);
            s16x4 pk = { (short)f2bf(v[0]), (short)f2bf(v[1]),
                         (short)f2bf(v[2]), (short)f2bf(v[3]) };
            *(s16x4*)&sX[row][128 + c4] = pk;
        }
        __syncthreads();

        f32x4 acc[8][2];
        #pragma unroll
        for (int m = 0; m < 8; ++m) {
            acc[m][0] = f32x4{0.f, 0.f, 0.f, 0.f};
            acc[m][1] = f32x4{0.f, 0.f, 0.f, 0.f};
        }
        #pragma unroll
        for (int ks = 0; ks < 6; ++ks) {
            #pragma unroll
            for (int m = 0; m < 8; ++m) {
                bf16x8 a = *(const bf16x8*)&sX[m * 16 + arow][ks * 32 + kr0];
                acc[m][0] = __builtin_amdgcn_mfma_f32_16x16x32_bf16(a, bfrag[ks][0], acc[m][0], 0, 0, 0);
                acc[m][1] = __builtin_amdgcn_mfma_f32_16x16x32_bf16(a, bfrag[ks][1], acc[m][1], 0, 0, 0);
            }
        }

        // --- relu + segmented max into LDS (in-CU ds atomics, order-insensitive)
        #pragma unroll
        for (int m = 0; m < 8; ++m) {
            #pragma unroll
            for (int r = 0; r < 4; ++r) {
                const int g = rowNode[m * 16 + rb + r];
                const float v0 = acc[m][0][r];
                const float v1 = acc[m][1][r];
                if (g < NODES_PER_BLK) {
                    if (v0 > 0.f) atomicMax((int*)&ymax[g][wave * 32 + col],      __float_as_int(v0));
                    if (v1 > 0.f) atomicMax((int*)&ymax[g][wave * 32 + col + 16], __float_as_int(v1));
                }
            }
        }
        __syncthreads();
    }

    // --- write bf16 gmax rows (each node owned by exactly this block)
    #pragma unroll
    for (int it = 0; it < 2; ++it) {
        const int i  = tid + it * 256;       // 512 x ushort4 = 16 rows x 128 cols
        const int g  = i >> 5;
        const int c4 = (i & 31) * 4;
        s16x4 pk = { (short)f2bf(ymax[g][c4]),     (short)f2bf(ymax[g][c4 + 1]),
                     (short)f2bf(ymax[g][c4 + 2]), (short)f2bf(ymax[g][c4 + 3]) };
        *(s16x4*)&gmax[(size_t)(nodeBase + g) * HID + c4] = pk;
    }
}

// ---------------- node MLP + residual ----------------
__global__ __launch_bounds__(256, 2)
void node_mlp(const float* __restrict__ H,
              const unsigned short* __restrict__ gmax,
              const float* __restrict__ W2,
              float* __restrict__ out) {
    __shared__ unsigned short sA[64][264];    // 256 + 8 pad; 33.8 KB

    const int tid  = threadIdx.x;
    const int wave = tid >> 6;
    const int lane = tid & 63;
    const int base = blockIdx.x * 64;

    const int col = lane & 15;
    const int kr0 = (lane >> 4) * 8;
    bf16x8 bfrag[8][2];
    #pragma unroll
    for (int ks = 0; ks < 8; ++ks) {
        #pragma unroll
        for (int nf = 0; nf < 2; ++nf) {
            const int n  = wave * 32 + nf * 16 + col;
            const int kb = ks * 32 + kr0;
            bf16x8 b;
            #pragma unroll
            for (int f = 0; f < 8; ++f) b[f] = (short)f2bf(W2[(kb + f) * HID + n]);
            bfrag[ks][nf] = b;
        }
    }

    // stage H (f32 -> bf16): 64 rows x 128 cols
    #pragma unroll
    for (int it = 0; it < 8; ++it) {
        const int i   = tid + it * 256;
        const int row = i >> 5;
        const int c4  = (i & 31) * 4;
        int node = base + row;
        if (node >= N_NODES) node = N_NODES - 1;
        const f32x4 v = *(const f32x4*)(H + (size_t)node * D_H + c4);
        s16x4 pk = { (short)f2bf(v[0]), (short)f2bf(v[1]),
                     (short)f2bf(v[2]), (short)f2bf(v[3]) };
        *(s16x4*)&sA[row][c4] = pk;
    }
    // stage gmax (already bf16): cols 128..255
    #pragma unroll
    for (int it = 0; it < 8; ++it) {
        const int i   = tid + it * 256;
        const int row = i >> 5;
        const int c4  = (i & 31) * 4;
        int node = base + row;
        if (node >= N_NODES) node = N_NODES - 1;
        *(s16x4*)&sA[row][128 + c4] = *(const s16x4*)(gmax + (size_t)node * HID + c4);
    }
    __syncthreads();

    f32x4 acc[4][2];
    #pragma unroll
    for (int m = 0; m < 4; ++m) {
        acc[m][0] = f32x4{0.f, 0.f, 0.f, 0.f};
        acc[m][1] = f32x4{0.f, 0.f, 0.f, 0.f};
    }
    const int arow = lane & 15;
    #pragma unroll
    for (int ks = 0; ks < 8; ++ks) {
        #pragma unroll
        for (int m = 0; m < 4; ++m) {
            bf16x8 a = *(const bf16x8*)&sA[m * 16 + arow][ks * 32 + kr0];
            acc[m][0] = __builtin_amdgcn_mfma_f32_16x16x32_bf16(a, bfrag[ks][0], acc[m][0], 0, 0, 0);
            acc[m][1] = __builtin_amdgcn_mfma_f32_16x16x32_bf16(a, bfrag[ks][1], acc[m][1], 0, 0, 0);
        }
    }

    const int rb = (lane >> 4) * 4;
    #pragma unroll
    for (int m = 0; m < 4; ++m) {
        #pragma unroll
        for (int r = 0; r < 4; ++r) {
            const int node = base + m * 16 + rb + r;
            if (node < N_NODES) {
                const size_t o = (size_t)node * HID + wave * 32 + col;
                out[o]      = fmaxf(acc[m][0][r], 0.f) + H[o];
                out[o + 16] = fmaxf(acc[m][1][r], 0.f) + H[o + 16];
            }
        }
    }
}

extern "C" void kernel_launch(void* const* d_in, const int* in_sizes, int n_in,
                              void* d_out, int out_size, void* d_ws, size_t ws_size,
                              hipStream_t stream) {
    const float* H   = (const float*)d_in[0];
    const int*   idx = (const int*)d_in[1];
    const float* Xe  = (const float*)d_in[2];
    const float* W1  = (const float*)d_in[3];
    const float* W2  = (const float*)d_in[4];
    float* out = (float*)d_out;

    // workspace layout (all offsets 256B-aligned); total ~16.8 MB
    char* ws = (char*)d_ws;
    unsigned short* gmax = (unsigned short*)(ws);          // 50000*128*2 = 12,800,000
    int* deg     = (int*)(ws + 12800000);                  // 200,000
    int* sc      = (int*)(ws + 13000192);                  // 200,000
    int* totals  = (int*)(ws + 13200384);                  // 512
    int* offsets = (int*)(ws + 13200896);                  // 200,004
    int* cursor  = (int*)(ws + 13401344);                  // 200,000
    int* perm    = (int*)(ws + 13601536);                  // 3,200,000

    zero_deg<<<(N_NODES / 4 + 255) / 256, 256, 0, stream>>>(deg);
    hist<<<N_EDGES / 256, 256, 0, stream>>>(idx, deg);
    scan_a<<<N_CHUNKS, SCAN_B, 0, stream>>>(deg, sc, totals);
    scan_b<<<1, 128, 0, stream>>>(totals);
    scan_c<<<N_CHUNKS, SCAN_B, 0, stream>>>(sc, totals, offsets, cursor);
    scatter<<<N_EDGES / 256, 256, 0, stream>>>(idx, cursor, perm);
    edge_sorted<<<N_BLOCKS, 256, 0, stream>>>(H, idx, Xe, W1, offsets, perm, gmax);
    node_mlp<<<(N_NODES + 63) / 64, 256, 0, stream>>>(H, gmax, W2, out);
}